// Round 7
// baseline (405.262 us; speedup 1.0000x reference)
//
#include <hip/hip_runtime.h>
#include <math.h>
#include <stdint.h>

// Problem constants (fixed by the harness/reference):
// B=2, S=8192, H=16, D=128, W=4 (window = W+1 = 5 taps)
constexpr int B = 2;
constexpr int S = 8192;
constexpr int H = 16;
constexpr int D = 128;
constexpr int W = 4;
constexpr int HD = H * D;                  // 2048 floats = 8 KB per s-row (ALL heads)
constexpr int L = 64;                      // s-rows per block
constexpr int NIT = L / 2;                 // 32 iterations x 2 s-rows
constexpr int SEG = S / L;                 // 128 segments per batch
constexpr int NR = 8;                      // ring slots (rows); slot = s & 7
constexpr float SCALE = 0.08838834764831845f;  // 1/sqrt(128)
constexpr int LDS_BYTES = NR * HD * 4 * 2;     // k ring + v ring = 131072 B

// DPP butterfly add: x += lanepermute(x). 0xB1=xor1, 0x4E=xor2,
// 0x141=row_half_mirror (xor4), 0x140=row_mirror (xor8). All VALU-pipe.
template <int CTRL>
__device__ __forceinline__ float dpp_xadd(float x) {
    int r = __builtin_amdgcn_update_dpp(0, __float_as_int(x), CTRL, 0xF, 0xF, false);
    return x + __int_as_float(r);
}
// Full reduction across a 16-lane group: 4 DPP steps, no DS ops.
__device__ __forceinline__ float group_reduce16(float p) {
    p = dpp_xadd<0xB1>(p);
    p = dpp_xadd<0x4E>(p);
    p = dpp_xadd<0x141>(p);
    p = dpp_xadd<0x140>(p);
    return p;
}
__device__ __forceinline__ float dot8(const float4& qa, const float4& qb,
                                      const float4& ka, const float4& kb) {
    return qa.x * ka.x + qa.y * ka.y + qa.z * ka.z + qa.w * ka.w +
           qb.x * kb.x + qb.y * kb.y + qb.z * kb.z + qb.w * kb.w;
}

// Async global->LDS DMA, 16B/lane; LDS dest = wave-uniform base + lane*16.
typedef const __attribute__((address_space(1))) uint32_t cg_u32;
typedef __attribute__((address_space(3))) uint32_t lds_u32;
__device__ __forceinline__ void gload_lds16(const float* g, float* l) {
    __builtin_amdgcn_global_load_lds((cg_u32*)g, (lds_u32*)l, 16, 0, 0);
}

// ROUND 7 = ROUND 6 RESUBMIT (round 6 was a broker/container infra failure,
// same as round 3; kernel re-audited: no deadlock, no OOB, no ring race).
// CONTIGUOUS-STREAM test. Rounds 0-5 all plateaued at 2.0-2.4 TB/s
// (vs 6.3 copy ubench) with ample parallelism -> service-rate ceiling for the
// shared pattern: every request was a 512B granule (one head) at 8KB stride.
// Round 5 falsified granule CO-RESIDENCY as the fix; this round tests
// INSTRUCTION-LEVEL contiguity: block = (batch, 64-s span) x ALL 16 heads,
// k/v staged per whole contiguous 8KB row [s,:,:] into an 8-slot LDS ring
// (slot = s&7, 128KB total) -- the DMA read stream is byte-identical to the
// 6.3TB/s copy ubench. Taps span 6 rows, so 2 slots are always free for the
// next iteration's 2-row prefetch. One s_barrier + one counted vmcnt(2) per
// iteration; q/a/b prefetched one iteration ahead into registers.
__global__ __launch_bounds__(512, 1) void gdr_kernel(
    const float* __restrict__ q, const float* __restrict__ k,
    const float* __restrict__ v, const float* __restrict__ a,
    const float* __restrict__ b, float* __restrict__ out)
{
    extern __shared__ __align__(16) float smem[];
    float* kr = smem;               // [NR][HD] k ring
    float* vr = smem + NR * HD;     // [NR][HD] v ring

    const int tid  = threadIdx.x;
    const int wave = tid >> 6;          // 0..7
    const int lane = tid & 63;
    const int grp  = tid >> 4;          // 0..31: output group
    const int roff = grp >> 4;          // 0/1: s-row within the iteration
    const int h    = grp & 15;          // head
    const int l4   = (tid & 15) * 4;    // float offset within head slice

    const int bid = blockIdx.x;
    const int seg = bid & (SEG - 1);
    const int bb  = bid >> 7;           // batch (SEG=128)
    const int s0  = seg * L;
    const int rowBase = bb * S;         // global s-row index base
    const bool lastBlk = (bid == B * SEG - 1);

    // Per-wave DMA chunk: wave w covers floats [w*256, w*256+256) of a row,
    // lane l the 16B at +l*4. 8 waves x 1KB = one full contiguous 8KB row.
    const int gOff = wave * 256 + lane * 4;
    const int lOff = wave * 256;        // wave-uniform LDS base offset

    // ---- prologue ----
    if (seg == 0) {
        // zero history rows -4..-1 -> slots 4..7 ((s)&7 for s=-4..-1)
        const float4 z = make_float4(0.f, 0.f, 0.f, 0.f);
        float4* kz = (float4*)(kr + 4 * HD);
        float4* vz = (float4*)(vr + 4 * HD);
        for (int i = tid; i < HD; i += 512) { kz[i] = z; vz[i] = z; }  // 4*HD/4
    }
    {
        const int rr0 = (seg == 0) ? 4 : 0;     // seg0: only rows 0,1 staged
        for (int rr = rr0; rr < 6; ++rr) {      // rows s0-4 .. s0+1
            const int r  = s0 - 4 + rr;
            const int gb = (rowBase + r) * HD + gOff;
            const int lb = (r & 7) * HD + lOff;
            gload_lds16(k + gb, kr + lb);
            gload_lds16(v + gb, vr + lb);
        }
    }

    // q/a/b for iteration 0 (this group's row s0+roff)
    const int sC0 = s0 + roff;
    const int eC0 = (rowBase + sC0) * HD + h * D + l4;
    float4 qa_c = *(const float4*)(q + eC0);
    float4 qb_c = *(const float4*)(q + eC0 + 64);
    float  a_c  = a[(rowBase + sC0) * H + h];
    float  b_c[W + 1];
#pragma unroll
    for (int d = 0; d <= W; ++d) {
        int j = sC0 - d; if (j < 0) j = 0;      // clamped tap has k=v=0 anyway
        b_c[d] = b[(rowBase + j) * H + h];
    }

    __syncthreads();   // drains prologue DMA (vmcnt 0) + publishes zero-fill

    for (int t = 0; t < NIT; ++t) {
        // Drain DMA(t)+q(t): >=10 VMEM ops (8 q/a/b + 2 stores) were issued
        // after the 4 DMA(t), so vmcnt(2) always fully drains DMA(t) while
        // leaving the previous iteration's 2 output stores in flight.
        asm volatile("s_waitcnt vmcnt(2)" ::: "memory");
        __builtin_amdgcn_s_barrier();
        __builtin_amdgcn_sched_barrier(0);   // rule #18: nothing hoists above

        // ---- issue DMA(t+1): rows s0+2t+2, s0+2t+3 (contiguous 16KB) ----
        // Their slots ((2t+2)&7,(2t+3)&7) are the 2 not read by compute(t).
        if (!(lastBlk && t == NIT - 1)) {    // only the very last row-pair is OOB
            const int r2  = s0 + 2 * t + 2;
            const int gb  = (rowBase + r2) * HD + gOff;
            const int lb0 = ((r2) & 7) * HD + lOff;
            const int lb1 = ((r2 + 1) & 7) * HD + lOff;
            gload_lds16(k + gb,      kr + lb0);
            gload_lds16(k + gb + HD, kr + lb1);
            gload_lds16(v + gb,      vr + lb0);
            gload_lds16(v + gb + HD, vr + lb1);
        }
        __builtin_amdgcn_sched_barrier(0);

        // ---- q/a/b prefetch for iteration t+1 (clamped; dead at t=NIT-1) ----
        const int tq = (t + 1 < NIT) ? (t + 1) : (NIT - 1);
        const int sN = s0 + 2 * tq + roff;
        const int eN = (rowBase + sN) * HD + h * D + l4;
        const float4 qa_n = *(const float4*)(q + eN);
        const float4 qb_n = *(const float4*)(q + eN + 64);
        const float  a_n  = a[(rowBase + sN) * H + h];
        float b_n[W + 1];
#pragma unroll
        for (int d = 0; d <= W; ++d) {
            int j = sN - d; if (j < 0) j = 0;
            b_n[d] = b[(rowBase + j) * H + h];
        }
        __builtin_amdgcn_sched_barrier(0);

        // ---- compute row s = s0+2t+roff from the LDS ring ----
        const int s = s0 + 2 * t + roff;
        float4 acca = make_float4(0.f, 0.f, 0.f, 0.f);
        float4 accb = acca, v0a = acca, v0b = acca;
#pragma unroll
        for (int d = 0; d <= W; ++d) {
            const int base = ((s - d) & 7) * HD + h * D + l4;  // (-x)&7 ok
            const float4 ka = *(const float4*)(kr + base);
            const float4 kb = *(const float4*)(kr + base + 64);
            const float4 va = *(const float4*)(vr + base);
            const float4 vb = *(const float4*)(vr + base + 64);
            float p = group_reduce16(dot8(qa_c, qb_c, ka, kb));
            const float g  = __builtin_amdgcn_rcpf(1.0f + __expf(-(a_c * b_c[d])));
            const float wg = p * SCALE * g;
            acca.x += wg * va.x; acca.y += wg * va.y;
            acca.z += wg * va.z; acca.w += wg * va.w;
            accb.x += wg * vb.x; accb.y += wg * vb.y;
            accb.z += wg * vb.z; accb.w += wg * vb.w;
            if (d == 0) { v0a = va; v0b = vb; }   // tap-0 v == v_s
        }
        if (s == 0) { acca = v0a; accb = v0b; }   // reference: out[0] = v_0
        const int eO = (rowBase + s) * HD + h * D + l4;
        *(float4*)(out + eO)      = acca;
        *(float4*)(out + eO + 64) = accb;

        // rotate prefetched q/a/b into current
        qa_c = qa_n; qb_c = qb_n; a_c = a_n;
#pragma unroll
        for (int d = 0; d <= W; ++d) b_c[d] = b_n[d];
    }
}

extern "C" void kernel_launch(void* const* d_in, const int* in_sizes, int n_in,
                              void* d_out, int out_size, void* d_ws, size_t ws_size,
                              hipStream_t stream) {
    const float* q = (const float*)d_in[0];
    const float* k = (const float*)d_in[1];
    const float* v = (const float*)d_in[2];
    const float* a = (const float*)d_in[3];
    const float* b = (const float*)d_in[4];
    float* out = (float*)d_out;

    // B(2) x SEG(128) = 256 blocks (one per CU, LDS-capped), 512 threads,
    // 128KB dynamic LDS (same size as the proven m201 template).
    const int blocks = B * SEG;
    gdr_kernel<<<blocks, 512, LDS_BYTES, stream>>>(q, k, v, a, b, out);
}